// Round 2
// baseline (476.919 us; speedup 1.0000x reference)
//
#include <hip/hip_runtime.h>

// ---- problem constants ----
#define D_DIM 1024
#define B_DIM 16
#define T_DIM 2048
#define M_TOT (B_DIM * T_DIM)   // 32768 rows
#define K_DIM 1024
#define LN_EPS 1e-5f
#define CHUNK 128
#define NCH (T_DIM / CHUNK)     // 16 chunks

typedef _Float16 half8 __attribute__((ext_vector_type(8)));
typedef float f32x4 __attribute__((ext_vector_type(4)));

// ---------------- fp32 -> fp16 conversion, 8 elems/thread ----------------
__global__ __launch_bounds__(256) void cvt_f32_f16(const float* __restrict__ in,
                                                   _Float16* __restrict__ out, int n8) {
    int i = blockIdx.x * blockDim.x + threadIdx.x;
    int stride = gridDim.x * blockDim.x;
    for (; i < n8; i += stride) {
        const float4* p = (const float4*)in + 2 * (size_t)i;
        float4 a = p[0], b = p[1];
        half8 h;
        h[0] = (_Float16)a.x; h[1] = (_Float16)a.y; h[2] = (_Float16)a.z; h[3] = (_Float16)a.w;
        h[4] = (_Float16)b.x; h[5] = (_Float16)b.y; h[6] = (_Float16)b.z; h[7] = (_Float16)b.w;
        ((half8*)out)[i] = h;
    }
}

// ---------------- fp16 MFMA GEMM, C[m][n] = sum_k A[m][k] * B[n][k] ----------------
// m97-style structure: 128x128 tile, BK=32, 4 waves (2x2), each wave 64x64 out,
// global_load_lds width=16 staging, 16x16x32 f16 MFMA.
#define BM 128
#define BN 128
#define BK 32

__device__ __forceinline__ void gl_lds16(const _Float16* g, _Float16* l) {
    __builtin_amdgcn_global_load_lds(
        (const __attribute__((address_space(1))) unsigned int*)g,
        (__attribute__((address_space(3))) unsigned int*)l,
        16, 0, 0);
}

// mode 0: out0[m*N + n] = (half)acc
// mode 1: n < D -> out0[m*D + n] = (half)sigmoid(acc) ; n >= D -> out1[m*D + n-D] = (half)acc
__global__ __launch_bounds__(256) void gemm_bt(const _Float16* __restrict__ A,
                                               const _Float16* __restrict__ Bm,
                                               int Mtiles, int N, int K,
                                               _Float16* __restrict__ out0,
                                               _Float16* __restrict__ out1,
                                               int mode) {
    __shared__ _Float16 As[BM * BK];
    __shared__ _Float16 Bs[BN * BK];

    int bid = blockIdx.x;
    int mt = bid % Mtiles, nt = bid / Mtiles;
    int m0 = mt * BM, n0 = nt * BN;
    int tid = threadIdx.x;
    int wid = tid >> 6, lane = tid & 63;
    int wr = wid >> 1, wc = wid & 1;     // 2x2 wave grid, each wave 64x64

    f32x4 acc[4][4];
#pragma unroll
    for (int i = 0; i < 4; i++)
#pragma unroll
        for (int j = 0; j < 4; j++) acc[i][j] = (f32x4)0.f;

    int r = lane & 15, kq = lane >> 4;   // frag row/col and k-quarter

    for (int kt = 0; kt < K; kt += BK) {
        __syncthreads();   // previous iter's ds_reads done before overwrite
        // stage A,B tiles: 128x32 halfs = 8KB = 512 chunks of 16B; 2 chunks/thread
#pragma unroll
        for (int j = 0; j < 2; ++j) {
            int f = j * 256 + tid;       // chunk id 0..511
            int row = f >> 2, kc = f & 3;
            // lds dest: wave-uniform base, hw adds lane*16B
            gl_lds16(A + (size_t)(m0 + row) * K + kt + kc * 8, As + (size_t)(j * 256 + wid * 64) * 8);
            gl_lds16(Bm + (size_t)(n0 + row) * K + kt + kc * 8, Bs + (size_t)(j * 256 + wid * 64) * 8);
        }
        __syncthreads();   // compiler drains vmcnt(0) before barrier

        half8 af[4], bf[4];
#pragma unroll
        for (int mi = 0; mi < 4; mi++)
            af[mi] = *(const half8*)&As[(wr * 64 + mi * 16 + r) * BK + kq * 8];
#pragma unroll
        for (int ni = 0; ni < 4; ni++)
            bf[ni] = *(const half8*)&Bs[(wc * 64 + ni * 16 + r) * BK + kq * 8];
#pragma unroll
        for (int mi = 0; mi < 4; mi++)
#pragma unroll
            for (int ni = 0; ni < 4; ni++)
                acc[mi][ni] = __builtin_amdgcn_mfma_f32_16x16x32_f16(af[mi], bf[ni], acc[mi][ni], 0, 0, 0);
    }

    // C/D layout: col = lane&15, row = (lane>>4)*4 + reg
    int rr = kq * 4;
#pragma unroll
    for (int mi = 0; mi < 4; mi++) {
        int mbase = m0 + wr * 64 + mi * 16 + rr;
#pragma unroll
        for (int ni = 0; ni < 4; ni++) {
            int n = n0 + wc * 64 + ni * 16 + r;
#pragma unroll
            for (int q = 0; q < 4; q++) {
                float v = acc[mi][ni][q];
                size_t m = (size_t)(mbase + q);
                if (mode == 1) {
                    if (n < D_DIM)
                        out0[m * D_DIM + n] = (_Float16)(1.f / (1.f + __expf(-v)));
                    else
                        out1[m * D_DIM + (n - D_DIM)] = (_Float16)v;
                } else {
                    out0[m * (size_t)N + n] = (_Float16)v;
                }
            }
        }
    }
}

// ---------------- chunked affine scan ----------------
// h_t = u_t * h_{t-1} + (1-u_t) * c_t  composes as h = A*h0 + B per chunk.
__global__ __launch_bounds__(256) void scan_pass1(const _Float16* __restrict__ u,
                                                  const _Float16* __restrict__ cd,
                                                  float* __restrict__ Ac, float* __restrict__ Bc) {
    int idx = blockIdx.x * 256 + threadIdx.x;   // (b*NCH + ch)*D + d
    int d = idx & (D_DIM - 1);
    int bc = idx >> 10;
    int b = bc >> 4, ch = bc & (NCH - 1);
    size_t base = ((size_t)b * T_DIM + (size_t)ch * CHUNK) * D_DIM + d;
    float A = 1.f, Bv = 0.f;
#pragma unroll 8
    for (int t = 0; t < CHUNK; ++t) {
        float ut = (float)u[base + (size_t)t * D_DIM];
        float ct = (float)cd[base + (size_t)t * D_DIM];
        A = A * ut;
        Bv = ut * Bv + (1.f - ut) * ct;
    }
    Ac[idx] = A;
    Bc[idx] = Bv;
}

__global__ __launch_bounds__(256) void scan_pass2(const float* __restrict__ Ac,
                                                  const float* __restrict__ Bc,
                                                  float* __restrict__ h0) {
    int idx = blockIdx.x * 256 + threadIdx.x;   // b*D + d, 16384 total
    int b = idx >> 10, d = idx & (D_DIM - 1);
    float h = 0.f;
#pragma unroll
    for (int ch = 0; ch < NCH; ++ch) {
        int k = (b * NCH + ch) * D_DIM + d;
        h0[k] = h;
        h = Ac[k] * h + Bc[k];
    }
}

__global__ __launch_bounds__(256) void scan_pass3(const _Float16* __restrict__ u,
                                                  const _Float16* __restrict__ cd,
                                                  const float* __restrict__ h0,
                                                  float* __restrict__ y) {
    int idx = blockIdx.x * 256 + threadIdx.x;
    int d = idx & (D_DIM - 1);
    int bc = idx >> 10;
    int b = bc >> 4, ch = bc & (NCH - 1);
    size_t base = ((size_t)b * T_DIM + (size_t)ch * CHUNK) * D_DIM + d;
    float h = h0[idx];
#pragma unroll 8
    for (int t = 0; t < CHUNK; ++t) {
        float ut = (float)u[base + (size_t)t * D_DIM];
        float ct = (float)cd[base + (size_t)t * D_DIM];
        h = ut * h + (1.f - ut) * ct;
        y[base + (size_t)t * D_DIM] = h;
    }
}

// ---------------- LayerNorm over D, in-place on y ----------------
__global__ __launch_bounds__(256) void layernorm_k(float* __restrict__ y,
                                                   const float* __restrict__ gamma,
                                                   const float* __restrict__ beta) {
    size_t row = blockIdx.x;
    float4* rp = (float4*)(y + row * D_DIM);
    int tid = threadIdx.x, lane = tid & 63, wid = tid >> 6;
    float4 v = rp[tid];
    float s = v.x + v.y + v.z + v.w;
    float q = v.x * v.x + v.y * v.y + v.z * v.z + v.w * v.w;
#pragma unroll
    for (int off = 32; off > 0; off >>= 1) {
        s += __shfl_xor(s, off);
        q += __shfl_xor(q, off);
    }
    __shared__ float ls[4], lq[4];
    if (lane == 0) { ls[wid] = s; lq[wid] = q; }
    __syncthreads();
    s = ls[0] + ls[1] + ls[2] + ls[3];
    q = lq[0] + lq[1] + lq[2] + lq[3];
    float mu = s * (1.f / D_DIM);
    float var = q * (1.f / D_DIM) - mu * mu;
    float rs = rsqrtf(var + LN_EPS);
    const float4 g = ((const float4*)gamma)[tid];
    const float4 be = ((const float4*)beta)[tid];
    float4 o;
    o.x = (v.x - mu) * rs * g.x + be.x;
    o.y = (v.y - mu) * rs * g.y + be.y;
    o.z = (v.z - mu) * rs * g.z + be.z;
    o.w = (v.w - mu) * rs * g.w + be.w;
    rp[tid] = o;
}

extern "C" void kernel_launch(void* const* d_in, const int* in_sizes, int n_in,
                              void* d_out, int out_size, void* d_ws, size_t ws_size,
                              hipStream_t stream) {
    const float* x       = (const float*)d_in[0];
    const float* W_in    = (const float*)d_in[1];
    const float* W_state = (const float*)d_in[2];
    const float* gamma   = (const float*)d_in[3];
    const float* beta    = (const float*)d_in[4];
    float* out = (float*)d_out;

    char* w = (char*)d_ws;
    size_t off = 0;
    auto carve = [&](size_t bytes) {
        void* p = w + off;
        off += (bytes + 255) & ~(size_t)255;
        return p;
    };
    _Float16* xh   = (_Float16*)carve((size_t)M_TOT * K_DIM * 2);       // 64 MiB
    _Float16* wih  = (_Float16*)carve((size_t)2 * D_DIM * K_DIM * 2);   // 4 MiB
    _Float16* wsh  = (_Float16*)carve((size_t)D_DIM * K_DIM * 2);       // 2 MiB
    _Float16* uarr = (_Float16*)carve((size_t)M_TOT * D_DIM * 2);       // 64 MiB
    _Float16* vxh  = (_Float16*)carve((size_t)M_TOT * D_DIM * 2);       // 64 MiB
    float* Ac = (float*)carve((size_t)B_DIM * NCH * D_DIM * 4);         // 1 MiB
    float* Bc = (float*)carve((size_t)B_DIM * NCH * D_DIM * 4);
    float* h0 = (float*)carve((size_t)B_DIM * NCH * D_DIM * 4);
    _Float16* candh = xh;   // xh is dead after GEMM1; reuse for cand

    // 1. cast inputs to fp16
    cvt_f32_f16<<<2048, 256, 0, stream>>>(x, xh, M_TOT * K_DIM / 8);
    cvt_f32_f16<<<512, 256, 0, stream>>>(W_in, wih, 2 * D_DIM * K_DIM / 8);
    cvt_f32_f16<<<256, 256, 0, stream>>>(W_state, wsh, D_DIM * K_DIM / 8);

    // 2. proj = x @ W_in^T -> u (sigmoid half), vx (half)
    gemm_bt<<<(M_TOT / BM) * (2 * D_DIM / BN), 256, 0, stream>>>(
        xh, wih, M_TOT / BM, 2 * D_DIM, K_DIM, uarr, vxh, 1);

    // 3. cand = vx @ W_state^T -> candh
    gemm_bt<<<(M_TOT / BM) * (D_DIM / BN), 256, 0, stream>>>(
        vxh, wsh, M_TOT / BM, D_DIM, K_DIM, candh, nullptr, 0);

    // 4. chunked affine scan -> y (into d_out)
    scan_pass1<<<(B_DIM * NCH * D_DIM) / 256, 256, 0, stream>>>(uarr, candh, Ac, Bc);
    scan_pass2<<<(B_DIM * D_DIM) / 256, 256, 0, stream>>>(Ac, Bc, h0);
    scan_pass3<<<(B_DIM * NCH * D_DIM) / 256, 256, 0, stream>>>(uarr, candh, h0, out);

    // 5. LayerNorm in-place on d_out
    layernorm_k<<<M_TOT, 256, 0, stream>>>(out, gamma, beta);
}

// Round 3
// 381.562 us; speedup vs baseline: 1.2499x; 1.2499x over previous
//
#include <hip/hip_runtime.h>

// ---- problem constants ----
#define D_DIM 1024
#define B_DIM 16
#define T_DIM 2048
#define M_TOT (B_DIM * T_DIM)   // 32768 rows
#define K_DIM 1024
#define LN_EPS 1e-5f
#define CHUNK 64
#define NCH (T_DIM / CHUNK)     // 32 chunks

typedef _Float16 half8 __attribute__((ext_vector_type(8)));
typedef _Float16 half4 __attribute__((ext_vector_type(4)));
typedef float f32x4 __attribute__((ext_vector_type(4)));

// ---------------- fp32 -> fp16 conversion, 8 elems/thread ----------------
__global__ __launch_bounds__(256) void cvt_f32_f16(const float* __restrict__ in,
                                                   _Float16* __restrict__ out, int n8) {
    int i = blockIdx.x * blockDim.x + threadIdx.x;
    int stride = gridDim.x * blockDim.x;
    for (; i < n8; i += stride) {
        const float4* p = (const float4*)in + 2 * (size_t)i;
        float4 a = p[0], b = p[1];
        half8 h;
        h[0] = (_Float16)a.x; h[1] = (_Float16)a.y; h[2] = (_Float16)a.z; h[3] = (_Float16)a.w;
        h[4] = (_Float16)b.x; h[5] = (_Float16)b.y; h[6] = (_Float16)b.z; h[7] = (_Float16)b.w;
        ((half8*)out)[i] = h;
    }
}

// ---------------- fp32 [1024][1024] -> fp16 transpose (for W_vx^T) ----------------
__global__ __launch_bounds__(256) void transpose_cvt(const float* __restrict__ in,
                                                     _Float16* __restrict__ out) {
    __shared__ _Float16 t[32][33];
    int bx = blockIdx.x * 32, by = blockIdx.y * 32;
    int tx = threadIdx.x, ty = threadIdx.y;   // (32, 8)
#pragma unroll
    for (int j = 0; j < 4; ++j)
        t[ty + 8 * j][tx] = (_Float16)in[(size_t)(by + ty + 8 * j) * 1024 + bx + tx];
    __syncthreads();
#pragma unroll
    for (int j = 0; j < 4; ++j)
        out[(size_t)(bx + ty + 8 * j) * 1024 + by + tx] = t[tx][ty + 8 * j];
}

// ---------------- fp16 MFMA GEMM, C[m][n] = sum_k A[m][k] * B[n][k] ----------------
#define BM 128
#define BN 128
#define BK 32

__device__ __forceinline__ void gl_lds16(const _Float16* g, _Float16* l) {
    __builtin_amdgcn_global_load_lds(
        (const __attribute__((address_space(1))) unsigned int*)g,
        (__attribute__((address_space(3))) unsigned int*)l,
        16, 0, 0);
}

// mode 0: out0[m*N + n] = (half)acc
// mode 1: n < D -> out0[m*D + n] = (half)sigmoid(acc) ; n >= D -> out1[m*D + n-D] = (half)acc
__global__ __launch_bounds__(256) void gemm_bt(const _Float16* __restrict__ A,
                                               const _Float16* __restrict__ Bm,
                                               int Mtiles, int N, int K,
                                               _Float16* __restrict__ out0,
                                               _Float16* __restrict__ out1,
                                               int mode) {
    __shared__ _Float16 As[BM * BK];
    __shared__ _Float16 Bs[BN * BK];

    int bid = blockIdx.x;
    int mt = bid % Mtiles, nt = bid / Mtiles;
    int m0 = mt * BM, n0 = nt * BN;
    int tid = threadIdx.x;
    int wid = tid >> 6, lane = tid & 63;
    int wr = wid >> 1, wc = wid & 1;     // 2x2 wave grid, each wave 64x64

    f32x4 acc[4][4];
#pragma unroll
    for (int i = 0; i < 4; i++)
#pragma unroll
        for (int j = 0; j < 4; j++) acc[i][j] = (f32x4)0.f;

    int r = lane & 15, kq = lane >> 4;

    for (int kt = 0; kt < K; kt += BK) {
        __syncthreads();
#pragma unroll
        for (int j = 0; j < 2; ++j) {
            int f = j * 256 + tid;       // chunk id 0..511
            int row = f >> 2, kc = f & 3;
            gl_lds16(A + (size_t)(m0 + row) * K + kt + kc * 8, As + (size_t)(j * 256 + wid * 64) * 8);
            gl_lds16(Bm + (size_t)(n0 + row) * K + kt + kc * 8, Bs + (size_t)(j * 256 + wid * 64) * 8);
        }
        __syncthreads();

        half8 af[4], bf[4];
#pragma unroll
        for (int mi = 0; mi < 4; mi++)
            af[mi] = *(const half8*)&As[(wr * 64 + mi * 16 + r) * BK + kq * 8];
#pragma unroll
        for (int ni = 0; ni < 4; ni++)
            bf[ni] = *(const half8*)&Bs[(wc * 64 + ni * 16 + r) * BK + kq * 8];
#pragma unroll
        for (int mi = 0; mi < 4; mi++)
#pragma unroll
            for (int ni = 0; ni < 4; ni++)
                acc[mi][ni] = __builtin_amdgcn_mfma_f32_16x16x32_f16(af[mi], bf[ni], acc[mi][ni], 0, 0, 0);
    }

    // C/D layout: col = lane&15, row = (lane>>4)*4 + reg
    int rr = kq * 4;
#pragma unroll
    for (int mi = 0; mi < 4; mi++) {
        int mbase = m0 + wr * 64 + mi * 16 + rr;
#pragma unroll
        for (int ni = 0; ni < 4; ni++) {
            int n = n0 + wc * 64 + ni * 16 + r;
#pragma unroll
            for (int q = 0; q < 4; q++) {
                float v = acc[mi][ni][q];
                size_t m = (size_t)(mbase + q);
                if (mode == 1) {
                    if (n < D_DIM)
                        out0[m * D_DIM + n] = (_Float16)(1.f / (1.f + __expf(-v)));
                    else
                        out1[m * D_DIM + (n - D_DIM)] = (_Float16)v;
                } else {
                    out0[m * (size_t)N + n] = (_Float16)v;
                }
            }
        }
    }
}

// ---------------- chunked affine scan (vectorized: 8 dims/thread) ----------------
// idx = (b*NCH + ch)*128 + dg ; d0 = dg*8
__global__ __launch_bounds__(256) void scan_pass1(const _Float16* __restrict__ u,
                                                  const _Float16* __restrict__ cd,
                                                  float* __restrict__ Ac, float* __restrict__ Bc) {
    int idx = blockIdx.x * 256 + threadIdx.x;
    int dg = idx & 127, bc = idx >> 7;
    int b = bc >> 5, ch = bc & (NCH - 1);
    int d0 = dg * 8;
    size_t base = ((size_t)b * T_DIM + (size_t)ch * CHUNK) * D_DIM + d0;
    float Aa[8], Bb[8];
#pragma unroll
    for (int j = 0; j < 8; ++j) { Aa[j] = 1.f; Bb[j] = 0.f; }
#pragma unroll 4
    for (int t = 0; t < CHUNK; ++t) {
        half8 u8 = *(const half8*)&u[base + (size_t)t * D_DIM];
        half8 c8 = *(const half8*)&cd[base + (size_t)t * D_DIM];
#pragma unroll
        for (int j = 0; j < 8; ++j) {
            float ut = (float)u8[j], ct = (float)c8[j];
            Aa[j] *= ut;
            Bb[j] = fmaf(ut, Bb[j], (1.f - ut) * ct);
        }
    }
    size_t o = (size_t)bc * D_DIM + d0;
    *(float4*)&Ac[o]     = *(float4*)&Aa[0];
    *(float4*)&Ac[o + 4] = *(float4*)&Aa[4];
    *(float4*)&Bc[o]     = *(float4*)&Bb[0];
    *(float4*)&Bc[o + 4] = *(float4*)&Bb[4];
}

// AcH0 doubles as h0 output (read a before overwrite, same pointer => ordered)
__global__ __launch_bounds__(256) void scan_pass2(float* __restrict__ AcH0,
                                                  const float* __restrict__ Bc) {
    int idx = blockIdx.x * 256 + threadIdx.x;   // b*D + d, 16384 total
    int b = idx >> 10, d = idx & (D_DIM - 1);
    float h = 0.f;
#pragma unroll
    for (int ch = 0; ch < NCH; ++ch) {
        size_t k = ((size_t)(b * NCH + ch) << 10) + d;
        float a = AcH0[k];
        float bv = Bc[k];
        AcH0[k] = h;
        h = fmaf(a, h, bv);
    }
}

// y written in fp16 over the u buffer (per-element read-before-write, dataflow-ordered)
__global__ __launch_bounds__(256) void scan_pass3(const _Float16* __restrict__ u,
                                                  const _Float16* __restrict__ cd,
                                                  const float* __restrict__ h0,
                                                  _Float16* __restrict__ y) {
    int idx = blockIdx.x * 256 + threadIdx.x;
    int dg = idx & 127, bc = idx >> 7;
    int b = bc >> 5, ch = bc & (NCH - 1);
    int d0 = dg * 8;
    size_t base = ((size_t)b * T_DIM + (size_t)ch * CHUNK) * D_DIM + d0;
    size_t o = (size_t)bc * D_DIM + d0;
    float h[8];
    *(float4*)&h[0] = *(const float4*)&h0[o];
    *(float4*)&h[4] = *(const float4*)&h0[o + 4];
#pragma unroll 4
    for (int t = 0; t < CHUNK; ++t) {
        half8 u8 = *(const half8*)&u[base + (size_t)t * D_DIM];
        half8 c8 = *(const half8*)&cd[base + (size_t)t * D_DIM];
        half8 yv;
#pragma unroll
        for (int j = 0; j < 8; ++j) {
            float ut = (float)u8[j], ct = (float)c8[j];
            h[j] = fmaf(ut, h[j] - ct, ct);
            yv[j] = (_Float16)h[j];
        }
        *(half8*)&y[base + (size_t)t * D_DIM] = yv;
    }
}

// ---------------- LayerNorm over D: fp16 y in, fp32 out ----------------
__global__ __launch_bounds__(256) void layernorm_k(const _Float16* __restrict__ y,
                                                   const float* __restrict__ gamma,
                                                   const float* __restrict__ beta,
                                                   float* __restrict__ outp) {
    size_t row = blockIdx.x;
    int tid = threadIdx.x, lane = tid & 63, wid = tid >> 6;
    half4 v4 = ((const half4*)(y + row * D_DIM))[tid];
    float4 v = {(float)v4[0], (float)v4[1], (float)v4[2], (float)v4[3]};
    float s = v.x + v.y + v.z + v.w;
    float q = v.x * v.x + v.y * v.y + v.z * v.z + v.w * v.w;
#pragma unroll
    for (int off = 32; off > 0; off >>= 1) {
        s += __shfl_xor(s, off);
        q += __shfl_xor(q, off);
    }
    __shared__ float ls[4], lq[4];
    if (lane == 0) { ls[wid] = s; lq[wid] = q; }
    __syncthreads();
    s = ls[0] + ls[1] + ls[2] + ls[3];
    q = lq[0] + lq[1] + lq[2] + lq[3];
    float mu = s * (1.f / D_DIM);
    float var = q * (1.f / D_DIM) - mu * mu;
    float rs = rsqrtf(var + LN_EPS);
    const float4 g = ((const float4*)gamma)[tid];
    const float4 be = ((const float4*)beta)[tid];
    float4 o;
    o.x = (v.x - mu) * rs * g.x + be.x;
    o.y = (v.y - mu) * rs * g.y + be.y;
    o.z = (v.z - mu) * rs * g.z + be.z;
    o.w = (v.w - mu) * rs * g.w + be.w;
    ((float4*)(outp + row * D_DIM))[tid] = o;
}

extern "C" void kernel_launch(void* const* d_in, const int* in_sizes, int n_in,
                              void* d_out, int out_size, void* d_ws, size_t ws_size,
                              hipStream_t stream) {
    const float* x       = (const float*)d_in[0];
    const float* W_in    = (const float*)d_in[1];
    const float* W_state = (const float*)d_in[2];
    const float* gamma   = (const float*)d_in[3];
    const float* beta    = (const float*)d_in[4];
    float* out = (float*)d_out;

    char* w = (char*)d_ws;
    size_t off = 0;
    auto carve = [&](size_t bytes) {
        void* p = w + off;
        off += (bytes + 255) & ~(size_t)255;
        return p;
    };
    _Float16* xh   = (_Float16*)carve((size_t)M_TOT * K_DIM * 2);           // 64 MiB
    _Float16* Wall = (_Float16*)carve((size_t)2 * D_DIM * K_DIM * 2);       // 4 MiB (W_g ; W_comb)
    _Float16* uarr = (_Float16*)carve((size_t)M_TOT * D_DIM * 2);           // 64 MiB (u, later y fp16)
    _Float16* cand = (_Float16*)carve((size_t)M_TOT * D_DIM * 2);           // 64 MiB
    char* scratch  = (char*)carve((size_t)4 * 1024 * 1024);                 // 4 MiB shared region
    // early use of scratch:
    _Float16* wvxT = (_Float16*)scratch;                                    // 2 MiB
    _Float16* wst  = (_Float16*)(scratch + 2 * 1024 * 1024);                // 2 MiB
    // late use of scratch (after W_comb GEMM is done):
    float* Ac = (float*)scratch;                                            // 2 MiB (also h0)
    float* Bc = (float*)(scratch + 2 * 1024 * 1024);                        // 2 MiB

    // 1. casts: x -> fp16 ; W_g -> Wall[0:1024] ; W_vx^T -> wvxT ; W_state -> wst
    cvt_f32_f16<<<2048, 256, 0, stream>>>(x, xh, M_TOT * K_DIM / 8);
    cvt_f32_f16<<<512, 256, 0, stream>>>(W_in, Wall, D_DIM * K_DIM / 8);
    transpose_cvt<<<dim3(32, 32), dim3(32, 8), 0, stream>>>(W_in + (size_t)D_DIM * K_DIM, wvxT);
    cvt_f32_f16<<<512, 256, 0, stream>>>(W_state, wst, D_DIM * K_DIM / 8);

    // 2. W_comb = W_state @ W_vx  ->  Wall[1024:2048]
    //    C[e][k] = sum_n W_state[e][n] * W_vxT[k][n]
    gemm_bt<<<8 * (D_DIM / BN), 256, 0, stream>>>(
        wst, wvxT, 8, D_DIM, K_DIM, Wall + (size_t)D_DIM * K_DIM, nullptr, 0);

    // 3. fused projection: [u | cand] = x @ Wall^T  (sigmoid on u half)
    gemm_bt<<<(M_TOT / BM) * (2 * D_DIM / BN), 256, 0, stream>>>(
        xh, Wall, M_TOT / BM, 2 * D_DIM, K_DIM, uarr, cand, 1);

    // 4. chunked affine scan
    scan_pass1<<<(B_DIM * NCH * 128) / 256, 256, 0, stream>>>(uarr, cand, Ac, Bc);
    scan_pass2<<<(B_DIM * D_DIM) / 256, 256, 0, stream>>>(Ac, Bc);
    scan_pass3<<<(B_DIM * NCH * 128) / 256, 256, 0, stream>>>(uarr, cand, Ac, uarr);

    // 5. LayerNorm: fp16 y -> fp32 out
    layernorm_k<<<M_TOT, 256, 0, stream>>>(uarr, gamma, beta, out);
}

// Round 4
// 351.669 us; speedup vs baseline: 1.3562x; 1.0850x over previous
//
#include <hip/hip_runtime.h>

// ---- problem constants ----
#define D_DIM 1024
#define B_DIM 16
#define T_DIM 2048
#define M_TOT (B_DIM * T_DIM)   // 32768 rows
#define K_DIM 1024
#define LN_EPS 1e-5f
#define CHUNK 64
#define NCH (T_DIM / CHUNK)     // 32 chunks

typedef _Float16 half8 __attribute__((ext_vector_type(8)));
typedef _Float16 half4 __attribute__((ext_vector_type(4)));
typedef float f32x4 __attribute__((ext_vector_type(4)));

// ---------------- fp32 -> fp16 conversion, 8 elems/thread ----------------
__global__ __launch_bounds__(256) void cvt_f32_f16(const float* __restrict__ in,
                                                   _Float16* __restrict__ out, int n8) {
    int i = blockIdx.x * blockDim.x + threadIdx.x;
    int stride = gridDim.x * blockDim.x;
    for (; i < n8; i += stride) {
        const float4* p = (const float4*)in + 2 * (size_t)i;
        float4 a = p[0], b = p[1];
        half8 h;
        h[0] = (_Float16)a.x; h[1] = (_Float16)a.y; h[2] = (_Float16)a.z; h[3] = (_Float16)a.w;
        h[4] = (_Float16)b.x; h[5] = (_Float16)b.y; h[6] = (_Float16)b.z; h[7] = (_Float16)b.w;
        ((half8*)out)[i] = h;
    }
}

// ---------------- fp32 [1024][1024] -> fp16 transpose (for W_vx^T) ----------------
__global__ __launch_bounds__(256) void transpose_cvt(const float* __restrict__ in,
                                                     _Float16* __restrict__ out) {
    __shared__ _Float16 t[32][33];
    int bx = blockIdx.x * 32, by = blockIdx.y * 32;
    int tx = threadIdx.x, ty = threadIdx.y;   // (32, 8)
#pragma unroll
    for (int j = 0; j < 4; ++j)
        t[ty + 8 * j][tx] = (_Float16)in[(size_t)(by + ty + 8 * j) * 1024 + bx + tx];
    __syncthreads();
#pragma unroll
    for (int j = 0; j < 4; ++j)
        out[(size_t)(bx + ty + 8 * j) * 1024 + by + tx] = t[tx][ty + 8 * j];
}

// ================= 256x256 8-phase fp16 MFMA GEMM (C = A * B^T) =================
// Tile 256x256, BK=64, 8 waves (2M x 4N), per-wave 128x64 output.
// LDS 128 KiB double-buffered; XOR-swizzled (T2) via pre-swizzled global source;
// 4 phases/K-tile x 16 MFMA, 1 half-tile staged per phase, counted vmcnt (T4),
// setprio around MFMA clusters (T5).

__device__ __forceinline__ void gl_lds16(const _Float16* g, _Float16* l) {
    __builtin_amdgcn_global_load_lds(
        (const __attribute__((address_space(1))) unsigned int*)g,
        (__attribute__((address_space(3))) unsigned int*)l,
        16, 0, 0);
}

// Stage one half-tile (128 rows x 64 cols fp16 = 16 KiB) into LDS.
// Linear LDS dest (gl_lds requirement) + inverse-XOR'd global source chunk,
// so a matching XOR on the read side yields conflict-free ds_read_b128.
__device__ __forceinline__ void stage_half(const _Float16* __restrict__ G, int ld,
                                           int row0, int kt,
                                           _Float16* lds_base, int wid, int lane) {
#pragma unroll
    for (int j = 0; j < 2; ++j) {
        int c0 = j * 512 + wid * 64;        // wave-uniform chunk base
        int c  = c0 + lane;                 // this lane's chunk 0..1023
        int rl = c >> 3;                    // row within half-tile (8 chunks/row)
        int ch = (c & 7) ^ (rl & 7);        // swizzled source 16B-chunk
        gl_lds16(G + (size_t)(row0 + rl) * ld + kt + ch * 8,
                 lds_base + (size_t)c0 * 8);
    }
}

// Fragment read with the same XOR -> lanes 0..15 spread over 8 bank-groups.
__device__ __forceinline__ half8 frag_ld(const _Float16* base, int row, int ksub, int kq) {
    int ch = ((ksub << 2) | kq) ^ (row & 7);
    return *(const half8*)(base + (size_t)row * 64 + ch * 8);
}

// mode 0: out0[m*N + n] = (half)acc
// mode 1: n < D -> out0[m*D + n] = (half)sigmoid(acc) ; n >= D -> out1[m*D + n-D] = (half)acc
__global__ __launch_bounds__(512) void gemm256(const _Float16* __restrict__ A,
                                               const _Float16* __restrict__ Bm,
                                               int Mtiles, int N, int K,
                                               _Float16* __restrict__ out0,
                                               _Float16* __restrict__ out1,
                                               int mode) {
    __shared__ _Float16 As[2][256][64];
    __shared__ _Float16 Bs[2][256][64];

    // XCD-aware swizzle (grid % 8 == 0); nt-major so each XCD chunk shares W panel.
    int nwg = gridDim.x;
    int bid = blockIdx.x;
    int cpx = nwg >> 3;
    int lin = (bid & 7) * cpx + (bid >> 3);
    int nt = lin / Mtiles, mt = lin % Mtiles;
    int m0 = mt * 256, n0 = nt * 256;

    int tid = threadIdx.x, wid = tid >> 6, lane = tid & 63;
    int wr = wid >> 2, wc = wid & 3;         // 2 x 4 wave grid
    int r = lane & 15, kq = lane >> 4;

    f32x4 acc[8][4];
#pragma unroll
    for (int i = 0; i < 8; i++)
#pragma unroll
        for (int j = 0; j < 4; j++) acc[i][j] = (f32x4)0.f;

    const int nkt = K >> 6;                  // 16 K-tiles

    // ---- prologue: stage tile0 fully + tile1.B1; keep tile1.B1 in flight ----
    stage_half(Bm, K, n0 + 0,   0,  &Bs[0][0][0],   wid, lane);  // t0.B1
    stage_half(Bm, K, n0 + 128, 0,  &Bs[0][128][0], wid, lane);  // t0.B2
    stage_half(A,  K, m0 + 0,   0,  &As[0][0][0],   wid, lane);  // t0.A1
    stage_half(A,  K, m0 + 128, 0,  &As[0][128][0], wid, lane);  // t0.A2
    stage_half(Bm, K, n0 + 0,   64, &Bs[1][0][0],   wid, lane);  // t1.B1
    asm volatile("s_waitcnt vmcnt(2)" ::: "memory");             // t0 landed
    __builtin_amdgcn_s_barrier();

    for (int t = 0; t < nkt; ++t) {
        const _Float16* Ac = &As[t & 1][0][0];
        const _Float16* Bc = &Bs[t & 1][0][0];
        int nb = (t & 1) ^ 1;
        int kt1 = (t + 1) << 6, kt2 = (t + 2) << 6;
        half8 a0[4], a1[4], b[4];

        // ---- phase 0: ksub0, mhalf0 ----
#pragma unroll
        for (int mi = 0; mi < 4; mi++) a0[mi] = frag_ld(Ac, wr * 128 + mi * 16 + r, 0, kq);
#pragma unroll
        for (int ni = 0; ni < 4; ni++) b[ni]  = frag_ld(Bc, wc * 64 + ni * 16 + r, 0, kq);
        if (t + 1 < nkt) stage_half(Bm, K, n0 + 128, kt1, &Bs[nb][128][0], wid, lane); // (t+1).B2
        __builtin_amdgcn_s_barrier();
        __builtin_amdgcn_s_setprio(1);
#pragma unroll
        for (int mi = 0; mi < 4; mi++)
#pragma unroll
            for (int ni = 0; ni < 4; ni++)
                acc[mi][ni] = __builtin_amdgcn_mfma_f32_16x16x32_f16(a0[mi], b[ni], acc[mi][ni], 0, 0, 0);
        __builtin_amdgcn_s_setprio(0);
        __builtin_amdgcn_s_barrier();

        // ---- phase 1: ksub0, mhalf1 (preload mhalf1 ksub1 too) ----
#pragma unroll
        for (int mi = 0; mi < 4; mi++) a0[mi] = frag_ld(Ac, wr * 128 + 64 + mi * 16 + r, 0, kq);
#pragma unroll
        for (int mi = 0; mi < 4; mi++) a1[mi] = frag_ld(Ac, wr * 128 + 64 + mi * 16 + r, 1, kq);
        if (t + 1 < nkt) stage_half(A, K, m0 + 0, kt1, &As[nb][0][0], wid, lane);      // (t+1).A1
        __builtin_amdgcn_s_barrier();
        __builtin_amdgcn_s_setprio(1);
#pragma unroll
        for (int mi = 0; mi < 4; mi++)
#pragma unroll
            for (int ni = 0; ni < 4; ni++)
                acc[4 + mi][ni] = __builtin_amdgcn_mfma_f32_16x16x32_f16(a0[mi], b[ni], acc[4 + mi][ni], 0, 0, 0);
        __builtin_amdgcn_s_setprio(0);
        __builtin_amdgcn_s_barrier();

        // ---- phase 2: ksub1, mhalf0 ----
#pragma unroll
        for (int mi = 0; mi < 4; mi++) a0[mi] = frag_ld(Ac, wr * 128 + mi * 16 + r, 1, kq);
#pragma unroll
        for (int ni = 0; ni < 4; ni++) b[ni]  = frag_ld(Bc, wc * 64 + ni * 16 + r, 1, kq);
        if (t + 1 < nkt) stage_half(A, K, m0 + 128, kt1, &As[nb][128][0], wid, lane);  // (t+1).A2
        __builtin_amdgcn_s_barrier();
        __builtin_amdgcn_s_setprio(1);
#pragma unroll
        for (int mi = 0; mi < 4; mi++)
#pragma unroll
            for (int ni = 0; ni < 4; ni++)
                acc[mi][ni] = __builtin_amdgcn_mfma_f32_16x16x32_f16(a0[mi], b[ni], acc[mi][ni], 0, 0, 0);
        __builtin_amdgcn_s_setprio(0);
        __builtin_amdgcn_s_barrier();

        // ---- phase 3: ksub1, mhalf1 ----
        if (t + 2 < nkt) stage_half(Bm, K, n0 + 0, kt2, &Bs[t & 1][0][0], wid, lane);  // (t+2).B1
        __builtin_amdgcn_s_barrier();
        __builtin_amdgcn_s_setprio(1);
#pragma unroll
        for (int mi = 0; mi < 4; mi++)
#pragma unroll
            for (int ni = 0; ni < 4; ni++)
                acc[4 + mi][ni] = __builtin_amdgcn_mfma_f32_16x16x32_f16(a1[mi], b[ni], acc[4 + mi][ni], 0, 0, 0);
        __builtin_amdgcn_s_setprio(0);
        if (t + 2 < nkt) {
            asm volatile("s_waitcnt vmcnt(2)" ::: "memory");   // (t+1) fully landed
        } else if (t + 1 < nkt) {
            asm volatile("s_waitcnt vmcnt(0)" ::: "memory");   // drain before last tile
        }
        __builtin_amdgcn_s_barrier();
    }

    // ---- epilogue: C/D layout col = lane&15, row = (lane>>4)*4 + q ----
    int rr = kq * 4;
#pragma unroll
    for (int mi = 0; mi < 8; mi++) {
        int mbase = m0 + wr * 128 + mi * 16 + rr;
#pragma unroll
        for (int ni = 0; ni < 4; ni++) {
            int n = n0 + wc * 64 + ni * 16 + r;
#pragma unroll
            for (int q = 0; q < 4; q++) {
                float v = acc[mi][ni][q];
                size_t m = (size_t)(mbase + q);
                if (mode == 1) {
                    if (n < D_DIM)
                        out0[m * D_DIM + n] = (_Float16)(1.f / (1.f + __expf(-v)));
                    else
                        out1[m * D_DIM + (n - D_DIM)] = (_Float16)v;
                } else {
                    out0[m * (size_t)N + n] = (_Float16)v;
                }
            }
        }
    }
}

// ---------------- chunked affine scan (vectorized: 8 dims/thread) ----------------
__global__ __launch_bounds__(256) void scan_pass1(const _Float16* __restrict__ u,
                                                  const _Float16* __restrict__ cd,
                                                  float* __restrict__ Ac, float* __restrict__ Bc) {
    int idx = blockIdx.x * 256 + threadIdx.x;
    int dg = idx & 127, bc = idx >> 7;
    int b = bc >> 5, ch = bc & (NCH - 1);
    int d0 = dg * 8;
    size_t base = ((size_t)b * T_DIM + (size_t)ch * CHUNK) * D_DIM + d0;
    float Aa[8], Bb[8];
#pragma unroll
    for (int j = 0; j < 8; ++j) { Aa[j] = 1.f; Bb[j] = 0.f; }
#pragma unroll 4
    for (int t = 0; t < CHUNK; ++t) {
        half8 u8 = *(const half8*)&u[base + (size_t)t * D_DIM];
        half8 c8 = *(const half8*)&cd[base + (size_t)t * D_DIM];
#pragma unroll
        for (int j = 0; j < 8; ++j) {
            float ut = (float)u8[j], ct = (float)c8[j];
            Aa[j] *= ut;
            Bb[j] = fmaf(ut, Bb[j], (1.f - ut) * ct);
        }
    }
    size_t o = (size_t)bc * D_DIM + d0;
    *(float4*)&Ac[o]     = *(float4*)&Aa[0];
    *(float4*)&Ac[o + 4] = *(float4*)&Aa[4];
    *(float4*)&Bc[o]     = *(float4*)&Bb[0];
    *(float4*)&Bc[o + 4] = *(float4*)&Bb[4];
}

__global__ __launch_bounds__(256) void scan_pass2(float* __restrict__ AcH0,
                                                  const float* __restrict__ Bc) {
    int idx = blockIdx.x * 256 + threadIdx.x;   // b*D + d, 16384 total
    int b = idx >> 10, d = idx & (D_DIM - 1);
    float h = 0.f;
#pragma unroll
    for (int ch = 0; ch < NCH; ++ch) {
        size_t k = ((size_t)(b * NCH + ch) << 10) + d;
        float a = AcH0[k];
        float bv = Bc[k];
        AcH0[k] = h;
        h = fmaf(a, h, bv);
    }
}

__global__ __launch_bounds__(256) void scan_pass3(const _Float16* __restrict__ u,
                                                  const _Float16* __restrict__ cd,
                                                  const float* __restrict__ h0,
                                                  _Float16* __restrict__ y) {
    int idx = blockIdx.x * 256 + threadIdx.x;
    int dg = idx & 127, bc = idx >> 7;
    int b = bc >> 5, ch = bc & (NCH - 1);
    int d0 = dg * 8;
    size_t base = ((size_t)b * T_DIM + (size_t)ch * CHUNK) * D_DIM + d0;
    size_t o = (size_t)bc * D_DIM + d0;
    float h[8];
    *(float4*)&h[0] = *(const float4*)&h0[o];
    *(float4*)&h[4] = *(const float4*)&h0[o + 4];
#pragma unroll 4
    for (int t = 0; t < CHUNK; ++t) {
        half8 u8 = *(const half8*)&u[base + (size_t)t * D_DIM];
        half8 c8 = *(const half8*)&cd[base + (size_t)t * D_DIM];
        half8 yv;
#pragma unroll
        for (int j = 0; j < 8; ++j) {
            float ut = (float)u8[j], ct = (float)c8[j];
            h[j] = fmaf(ut, h[j] - ct, ct);
            yv[j] = (_Float16)h[j];
        }
        *(half8*)&y[base + (size_t)t * D_DIM] = yv;
    }
}

// ---------------- LayerNorm over D: fp16 y in, fp32 out ----------------
__global__ __launch_bounds__(256) void layernorm_k(const _Float16* __restrict__ y,
                                                   const float* __restrict__ gamma,
                                                   const float* __restrict__ beta,
                                                   float* __restrict__ outp) {
    size_t row = blockIdx.x;
    int tid = threadIdx.x, lane = tid & 63, wid = tid >> 6;
    half4 v4 = ((const half4*)(y + row * D_DIM))[tid];
    float4 v = {(float)v4[0], (float)v4[1], (float)v4[2], (float)v4[3]};
    float s = v.x + v.y + v.z + v.w;
    float q = v.x * v.x + v.y * v.y + v.z * v.z + v.w * v.w;
#pragma unroll
    for (int off = 32; off > 0; off >>= 1) {
        s += __shfl_xor(s, off);
        q += __shfl_xor(q, off);
    }
    __shared__ float ls[4], lq[4];
    if (lane == 0) { ls[wid] = s; lq[wid] = q; }
    __syncthreads();
    s = ls[0] + ls[1] + ls[2] + ls[3];
    q = lq[0] + lq[1] + lq[2] + lq[3];
    float mu = s * (1.f / D_DIM);
    float var = q * (1.f / D_DIM) - mu * mu;
    float rs = rsqrtf(var + LN_EPS);
    const float4 g = ((const float4*)gamma)[tid];
    const float4 be = ((const float4*)beta)[tid];
    float4 o;
    o.x = (v.x - mu) * rs * g.x + be.x;
    o.y = (v.y - mu) * rs * g.y + be.y;
    o.z = (v.z - mu) * rs * g.z + be.z;
    o.w = (v.w - mu) * rs * g.w + be.w;
    ((float4*)(outp + row * D_DIM))[tid] = o;
}

extern "C" void kernel_launch(void* const* d_in, const int* in_sizes, int n_in,
                              void* d_out, int out_size, void* d_ws, size_t ws_size,
                              hipStream_t stream) {
    const float* x       = (const float*)d_in[0];
    const float* W_in    = (const float*)d_in[1];
    const float* W_state = (const float*)d_in[2];
    const float* gamma   = (const float*)d_in[3];
    const float* beta    = (const float*)d_in[4];
    float* out = (float*)d_out;

    char* w = (char*)d_ws;
    size_t off = 0;
    auto carve = [&](size_t bytes) {
        void* p = w + off;
        off += (bytes + 255) & ~(size_t)255;
        return p;
    };
    _Float16* xh   = (_Float16*)carve((size_t)M_TOT * K_DIM * 2);           // 64 MiB
    _Float16* Wall = (_Float16*)carve((size_t)2 * D_DIM * K_DIM * 2);       // 4 MiB (W_g ; W_comb)
    _Float16* uarr = (_Float16*)carve((size_t)M_TOT * D_DIM * 2);           // 64 MiB (u, later y fp16)
    _Float16* cand = (_Float16*)carve((size_t)M_TOT * D_DIM * 2);           // 64 MiB
    char* scratch  = (char*)carve((size_t)4 * 1024 * 1024);                 // 4 MiB shared region
    _Float16* wvxT = (_Float16*)scratch;                                    // 2 MiB (early)
    _Float16* wst  = (_Float16*)(scratch + 2 * 1024 * 1024);                // 2 MiB (early)
    float* Ac = (float*)scratch;                                            // 2 MiB (late, also h0)
    float* Bc = (float*)(scratch + 2 * 1024 * 1024);                        // 2 MiB (late)

    // 1. casts: x -> fp16 ; W_g -> Wall[0:1024] ; W_vx^T -> wvxT ; W_state -> wst
    cvt_f32_f16<<<2048, 256, 0, stream>>>(x, xh, M_TOT * K_DIM / 8);
    cvt_f32_f16<<<512, 256, 0, stream>>>(W_in, Wall, D_DIM * K_DIM / 8);
    transpose_cvt<<<dim3(32, 32), dim3(32, 8), 0, stream>>>(W_in + (size_t)D_DIM * K_DIM, wvxT);
    cvt_f32_f16<<<512, 256, 0, stream>>>(W_state, wst, D_DIM * K_DIM / 8);

    // 2. W_comb = W_state @ W_vx -> Wall[1024:2048]  (M=1024: 4x4=16 blocks)
    gemm256<<<16, 512, 0, stream>>>(wst, wvxT, 4, D_DIM, K_DIM,
                                    Wall + (size_t)D_DIM * K_DIM, nullptr, 0);

    // 3. fused projection: [u | cand] = x @ Wall^T  (sigmoid on u half)
    gemm256<<<(M_TOT / 256) * (2 * D_DIM / 256), 512, 0, stream>>>(
        xh, Wall, M_TOT / 256, 2 * D_DIM, K_DIM, uarr, cand, 1);

    // 4. chunked affine scan
    scan_pass1<<<(B_DIM * NCH * 128) / 256, 256, 0, stream>>>(uarr, cand, Ac, Bc);
    scan_pass2<<<(B_DIM * D_DIM) / 256, 256, 0, stream>>>(Ac, Bc);
    scan_pass3<<<(B_DIM * NCH * 128) / 256, 256, 0, stream>>>(uarr, cand, Ac, uarr);

    // 5. LayerNorm: fp16 y -> fp32 out
    layernorm_k<<<M_TOT, 256, 0, stream>>>(uarr, gamma, beta, out);
}